// Round 1
// baseline (975.313 us; speedup 1.0000x reference)
//
#include <hip/hip_runtime.h>
#include <math.h>

#define B_    16
#define C_    256
#define H_    200
#define W_    200
#define NBOX  100
#define HID   256
#define OUTK  7
#define ROI_DIM 12544   // C_ * 49
#define NCLS  4

// ---------------------------------------------------------------- K1: ROI align
__global__ __launch_bounds__(256) void roi_pool_kernel(
    const float* __restrict__ feat, const float* __restrict__ boxes,
    float* __restrict__ pooled)
{
  int bn = blockIdx.x;              // 0..1599
  int b  = bn / NBOX;
  const float* bx = boxes + (size_t)bn * 4;
  float x1 = bx[0] - 0.5f, y1 = bx[1] - 0.5f;
  float x2 = bx[2] - 0.5f, y2 = bx[3] - 0.5f;
  float bh = (y2 - y1) * (1.0f / OUTK);
  float bw = (x2 - x1) * (1.0f / OUTK);

  // separable sample tables: 14 y-samples (i*2+sy), 14 x-samples (j*2+sx)
  __shared__ int   iy0[14], iy1[14], ix0[14], ix1[14];
  __shared__ float fly[14], flx[14], fvy[14], fvx[14];
  int tid = threadIdx.x;
  if (tid < 14) {
    int i = tid >> 1, s = tid & 1;
    float yy = y1 + ((float)i + ((float)s + 0.5f) * 0.5f) * bh;
    float v  = (yy >= -1.0f && yy <= (float)H_) ? 1.0f : 0.0f;
    float yc = fminf(fmaxf(yy, 0.0f), (float)(H_ - 1));
    int y0 = (int)floorf(yc);
    iy0[tid] = y0;
    iy1[tid] = min(y0 + 1, H_ - 1);
    fly[tid] = yc - (float)y0;
    fvy[tid] = v;
  } else if (tid >= 16 && tid < 30) {
    int t = tid - 16;
    int j = t >> 1, s = t & 1;
    float xx = x1 + ((float)j + ((float)s + 0.5f) * 0.5f) * bw;
    float v  = (xx >= -1.0f && xx <= (float)W_) ? 1.0f : 0.0f;
    float xc = fminf(fmaxf(xx, 0.0f), (float)(W_ - 1));
    int x0 = (int)floorf(xc);
    ix0[t] = x0;
    ix1[t] = min(x0 + 1, W_ - 1);
    flx[t] = xc - (float)x0;
    fvx[t] = v;
  }
  __syncthreads();

  const float* fb = feat + (size_t)b * (C_ * H_ * W_);
  float* po = pooled + (size_t)bn * ROI_DIM;

  // 12544 = 49 * 256 exactly: each thread does 49 (c,bin) items
  for (int idx = tid; idx < ROI_DIM; idx += 256) {
    int c   = idx / 49;
    int bin = idx - c * 49;
    int i   = bin / 7;
    int j   = bin - i * 7;
    const float* fc = fb + (size_t)c * (H_ * W_);
    float sum = 0.0f;
    #pragma unroll
    for (int sy = 0; sy < 2; ++sy) {
      int yi = i * 2 + sy;
      int y0 = iy0[yi], y1i = iy1[yi];
      float ly = fly[yi], hy = 1.0f - ly, vy = fvy[yi];
      const float* r0 = fc + y0  * W_;
      const float* r1 = fc + y1i * W_;
      #pragma unroll
      for (int sx = 0; sx < 2; ++sx) {
        int xi = j * 2 + sx;
        int x0 = ix0[xi], x1i = ix1[xi];
        float lx = flx[xi], hx = 1.0f - lx;
        float v = r0[x0] * (hy * hx) + r0[x1i] * (hy * lx)
                + r1[x0] * (ly * hx) + r1[x1i] * (ly * lx);
        sum += v * (vy * fvx[xi]);
      }
    }
    po[idx] = sum * 0.25f;
  }
}

// ---------------------------------------------------------------- K2: token init (bias)
__global__ __launch_bounds__(256) void token_init_kernel(
    const float* __restrict__ b_roi, float* __restrict__ tokens)
{
  int i = blockIdx.x * 256 + threadIdx.x;   // 409600 total
  tokens[i] = b_roi[i & 255];
}

// ---------------------------------------------------------------- K3: tokens += pooled @ w_roi^T  (NT gemm, K-split)
#define MT 64
#define NT 128
#define KC 16
#define KSPLIT 8
__global__ __launch_bounds__(256) void gemm_kernel(
    const float* __restrict__ A,    // pooled [1600][12544]
    const float* __restrict__ Bw,   // w_roi  [256][12544]
    float* __restrict__ Cc)         // tokens [1600][256]
{
  __shared__ __align__(16) float As[KC][MT + 4];   // k-major, padded
  __shared__ __align__(16) float Bs[KC][NT + 4];
  int tid = threadIdx.x;
  int m0 = blockIdx.x * MT;
  int n0 = blockIdx.y * NT;
  const int KRANGE = ROI_DIM / KSPLIT;  // 1568 = 98 * 16
  int k0 = blockIdx.z * KRANGE;

  int tn = tid & 15;    // col group: 8 cols
  int tm = tid >> 4;    // row group: 4 rows

  float acc[4][8];
  #pragma unroll
  for (int r = 0; r < 4; ++r)
    #pragma unroll
    for (int s = 0; s < 8; ++s) acc[r][s] = 0.0f;

  for (int kc = 0; kc < KRANGE; kc += KC) {
    int kg = k0 + kc;
    {   // A: 64 rows x 16 k -> transposed store
      int m  = tid >> 2;
      int k4 = (tid & 3) * 4;
      const float4 av = *(const float4*)(A + (size_t)(m0 + m) * ROI_DIM + kg + k4);
      As[k4 + 0][m] = av.x; As[k4 + 1][m] = av.y;
      As[k4 + 2][m] = av.z; As[k4 + 3][m] = av.w;
    }
    #pragma unroll
    for (int r2 = 0; r2 < 2; ++r2) {  // B: 128 rows x 16 k
      int l  = tid + r2 * 256;
      int n  = l >> 2;
      int k4 = (l & 3) * 4;
      const float4 bv = *(const float4*)(Bw + (size_t)(n0 + n) * ROI_DIM + kg + k4);
      Bs[k4 + 0][n] = bv.x; Bs[k4 + 1][n] = bv.y;
      Bs[k4 + 2][n] = bv.z; Bs[k4 + 3][n] = bv.w;
    }
    __syncthreads();
    #pragma unroll
    for (int kk = 0; kk < KC; ++kk) {
      float av[4], bv[8];
      *(float4*)av       = *(const float4*)&As[kk][tm * 4];
      *(float4*)bv       = *(const float4*)&Bs[kk][tn * 8];
      *(float4*)(bv + 4) = *(const float4*)&Bs[kk][tn * 8 + 4];
      #pragma unroll
      for (int r = 0; r < 4; ++r)
        #pragma unroll
        for (int s = 0; s < 8; ++s)
          acc[r][s] += av[r] * bv[s];
    }
    __syncthreads();
  }
  #pragma unroll
  for (int r = 0; r < 4; ++r) {
    int row = m0 + tm * 4 + r;
    #pragma unroll
    for (int s = 0; s < 8; ++s)
      atomicAdd(&Cc[(size_t)row * HID + n0 + tn * 8 + s], acc[r][s]);
  }
}

// ---------------------------------------------------------------- K4: attention + LN + MLP (one block per batch)
__global__ __launch_bounds__(256) void head_kernel(
    const float* __restrict__ tokens, const float* __restrict__ sev_q,
    const float* __restrict__ w_in,  const float* __restrict__ b_in,
    const float* __restrict__ w_out, const float* __restrict__ b_out,
    const float* __restrict__ ln_g,  const float* __restrict__ ln_b,
    const float* __restrict__ w1,    const float* __restrict__ b1,
    const float* __restrict__ w2,    const float* __restrict__ b2,
    float* __restrict__ outp)
{
  __shared__ float qh_s[256], qkv_s[1024], qkb_s[4];
  __shared__ float sc_s[400], att_s[400], tbar_s[1024];
  __shared__ float ctx_s[256], o_s[256], x_s[256], h1_s[256], red_s[8];
  int b = blockIdx.x, tid = threadIdx.x;
  const float* tok = tokens + (size_t)b * NBOX * HID;

  // qh = sev_q @ Wq^T + bq
  {
    const float* wq = w_in + (size_t)tid * HID;
    float a = 0.0f;
    for (int e = 0; e < HID; ++e) a += sev_q[e] * wq[e];
    qh_s[tid] = a + b_in[tid];
  }
  __syncthreads();
  if (tid < 4) {   // qh . bk  (per head)
    float a = 0.0f;
    for (int d = 0; d < 64; ++d) a += qh_s[tid * 64 + d] * b_in[256 + tid * 64 + d];
    qkb_s[tid] = a;
  }
  // qk_vec[h][e] = sum_d qh[h,d] * Wk[h*64+d][e]
  #pragma unroll
  for (int r = 0; r < 4; ++r) {
    int p = tid + r * 256;
    int h = p >> 8, e = p & 255;
    float a = 0.0f;
    for (int d = 0; d < 64; ++d)
      a += qh_s[h * 64 + d] * w_in[(size_t)(256 + h * 64 + d) * HID + e];
    qkv_s[p] = a;
  }
  __syncthreads();
  // scores[h][t]
  for (int p = tid; p < 4 * NBOX; p += 256) {
    int h = p / NBOX, t = p - h * NBOX;
    const float* tr = tok + (size_t)t * HID;
    const float* qv = qkv_s + h * 256;
    float a = 0.0f;
    for (int e = 0; e < HID; ++e) a += qv[e] * tr[e];
    sc_s[p] = (a + qkb_s[h]) * 0.125f;   // / sqrt(64)
  }
  __syncthreads();
  if (tid < 4) {   // softmax per head over 100
    float mx = -1e30f;
    for (int t = 0; t < NBOX; ++t) mx = fmaxf(mx, sc_s[tid * NBOX + t]);
    float sm = 0.0f;
    for (int t = 0; t < NBOX; ++t) {
      float e = expf(sc_s[tid * NBOX + t] - mx);
      att_s[tid * NBOX + t] = e; sm += e;
    }
    float inv = 1.0f / sm;
    for (int t = 0; t < NBOX; ++t) att_s[tid * NBOX + t] *= inv;
  }
  __syncthreads();
  // tbar[h][e] = sum_t att[h][t] * tok[t][e]
  #pragma unroll
  for (int r = 0; r < 4; ++r) {
    int p = tid + r * 256;
    int h = p >> 8, e = p & 255;
    float a = 0.0f;
    for (int t = 0; t < NBOX; ++t) a += att_s[h * NBOX + t] * tok[(size_t)t * HID + e];
    tbar_s[p] = a;
  }
  __syncthreads();
  // ctx[hd] = tbar[h] . Wv[hd] + bv[hd]
  {
    int h = tid >> 6;
    const float* wv = w_in + (size_t)(512 + tid) * HID;
    const float* tb = tbar_s + h * 256;
    float a = 0.0f;
    for (int e = 0; e < HID; ++e) a += tb[e] * wv[e];
    ctx_s[tid] = a + b_in[512 + tid];
  }
  __syncthreads();
  // o = ctx @ Wout^T + b_out
  {
    const float* wo = w_out + (size_t)tid * HID;
    float a = 0.0f;
    for (int k = 0; k < HID; ++k) a += ctx_s[k] * wo[k];
    o_s[tid] = a + b_out[tid];
  }
  __syncthreads();
  // LayerNorm (biased var)
  {
    float v = o_s[tid];
    float s1 = v, s2 = v * v;
    #pragma unroll
    for (int off = 32; off > 0; off >>= 1) {
      s1 += __shfl_down(s1, off);
      s2 += __shfl_down(s2, off);
    }
    if ((tid & 63) == 0) { red_s[(tid >> 6) * 2] = s1; red_s[(tid >> 6) * 2 + 1] = s2; }
    __syncthreads();
    float sum = red_s[0] + red_s[2] + red_s[4] + red_s[6];
    float ssq = red_s[1] + red_s[3] + red_s[5] + red_s[7];
    float mu  = sum * (1.0f / 256.0f);
    float var = ssq * (1.0f / 256.0f) - mu * mu;
    float inv = rsqrtf(var + 1e-5f);
    x_s[tid] = (v - mu) * inv * ln_g[tid] + ln_b[tid];
  }
  __syncthreads();
  // h1 = relu(x @ W1^T + b1)
  {
    const float* wr = w1 + (size_t)tid * HID;
    float a = 0.0f;
    for (int k = 0; k < HID; ++k) a += x_s[k] * wr[k];
    h1_s[tid] = fmaxf(a + b1[tid], 0.0f);
  }
  __syncthreads();
  // out = h1 @ W2^T + b2
  if (tid < NCLS) {
    const float* wr = w2 + (size_t)tid * HID;
    float a = 0.0f;
    for (int k = 0; k < HID; ++k) a += h1_s[k] * wr[k];
    outp[b * NCLS + tid] = a + b2[tid];
  }
}

// ---------------------------------------------------------------- launch
extern "C" void kernel_launch(void* const* d_in, const int* in_sizes, int n_in,
                              void* d_out, int out_size, void* d_ws, size_t ws_size,
                              hipStream_t stream) {
  (void)in_sizes; (void)n_in; (void)out_size; (void)ws_size;
  const float* feat  = (const float*)d_in[0];
  const float* boxes = (const float*)d_in[1];
  const float* w_roi = (const float*)d_in[2];
  const float* b_roi = (const float*)d_in[3];
  const float* sev_q = (const float*)d_in[4];
  const float* w_in  = (const float*)d_in[5];
  const float* b_in  = (const float*)d_in[6];
  const float* w_out = (const float*)d_in[7];
  const float* b_out = (const float*)d_in[8];
  const float* ln_g  = (const float*)d_in[9];
  const float* ln_b  = (const float*)d_in[10];
  const float* w1    = (const float*)d_in[11];
  const float* b1    = (const float*)d_in[12];
  const float* w2    = (const float*)d_in[13];
  const float* b2    = (const float*)d_in[14];
  float* out = (float*)d_out;

  float* pooled = (float*)d_ws;                          // 1600*12544 f32
  float* tokens = pooled + (size_t)B_ * NBOX * ROI_DIM;  // 1600*256  f32

  roi_pool_kernel  <<<B_ * NBOX, 256, 0, stream>>>(feat, boxes, pooled);
  token_init_kernel<<<(B_ * NBOX * HID) / 256, 256, 0, stream>>>(b_roi, tokens);
  gemm_kernel      <<<dim3((B_ * NBOX) / MT, HID / NT, KSPLIT), 256, 0, stream>>>(pooled, w_roi, tokens);
  head_kernel      <<<B_, 256, 0, stream>>>(tokens, sev_q, w_in, b_in, w_out, b_out,
                                            ln_g, ln_b, w1, b1, w2, b2, out);
}